// Round 5
// baseline (740.050 us; speedup 1.0000x reference)
//
#include <hip/hip_runtime.h>
#include <math.h>

// NS=64 NG=3 W=128 L=1024 M=32 TD=64 CD=128 NB=4 B=256
// fr stored bf16 [b][l][c] (channel-contiguous): combine/proj GEMMs read all
// operands directly (no staging); dft does the one LDS transpose per pass.

typedef unsigned short u16;
typedef unsigned int u32;
typedef __attribute__((ext_vector_type(8))) short bf16x8;
typedef __attribute__((ext_vector_type(4))) float f32x4;

#define MFMA(a,b,c) __builtin_amdgcn_mfma_f32_16x16x32_bf16((a),(b),(c),0,0,0)

__device__ __forceinline__ float gelu_f(float x){
  float x2 = x*x;
  float p  = __builtin_fmaf(0.10294323f, x2, 2.3022081f);
  float t  = __builtin_amdgcn_exp2f(x*p);
  float r  = __builtin_amdgcn_rcpf(t + 1.0f);
  return __builtin_fmaf(-x, r, x);
}
__device__ __forceinline__ u16 f2bf(float f){
  u32 u = __float_as_uint(f);
  u32 r = (u + 0x7FFFu + ((u>>16)&1u)) >> 16;
  return (u16)r;
}
__device__ __forceinline__ float bf2f(u32 u){ return __uint_as_float(u<<16); }
__device__ __forceinline__ int SW3(int x){ return ((x&7) ^ ((x>>4)&7)); }
__device__ __forceinline__ int SWP(int x){ return ((x&7) ^ ((x>>3)&7)) & 7; }
__device__ __forceinline__ int SWD(int c, int g){ return (g ^ (c&7) ^ ((c>>3)&7)) & 7; }

// ---- tables: POST f32[1024l][128c]; FtabT bf16[64q][1024l]; GT bf16[1024l][64q];
//      cwb bf16(4x128x128); w1b(64x128); w2b(64x64) ----
__global__ void k_tables(float* __restrict__ POST, u16* __restrict__ FtabT,
                         u16* __restrict__ GT, const float* __restrict__ conw,
                         u16* __restrict__ cwb, const float* __restrict__ pw1,
                         u16* __restrict__ w1b, const float* __restrict__ pw2,
                         u16* __restrict__ w2b){
  int idx = blockIdx.x*blockDim.x + threadIdx.x;
  if (idx < 128*1024){
    int l = idx >> 7, c = idx & 127;
    int j = c >> 1;
    float d = exp2f(-(float)j*(13.287712379549449f/64.0f));
    float ang = (float)l*d;
    POST[idx] = (c&1) ? cosf(ang) : sinf(ang);
  }
  if (idx < 64*1024){
    int q = idx >> 10, l = idx & 1023;
    int k = q >> 1;
    int m = (k*l) & 1023;
    float s, c;
    sincospif((float)m*(1.0f/512.0f), &s, &c);
    FtabT[q*1024 + l] = f2bf((q&1) ? -s : c);
  }
  if (idx < 64*1024){
    int l = idx >> 6, q = idx & 63;
    int k = q >> 1;
    int m = (k*l) & 1023;
    float s, c;
    sincospif((float)m*(1.0f/512.0f), &s, &c);
    float sc = (k==0) ? (1.0f/1024.0f) : (2.0f/1024.0f);
    float v = (q&1) ? ((k==0) ? 0.0f : -sc*s) : sc*c;
    GT[l*64 + q] = f2bf(v);
  }
  if (idx < 4*128*128) cwb[idx] = f2bf(conw[idx]);
  if (idx < 64*128)    w1b[idx] = f2bf(pw1[idx]);
  if (idx < 64*64)     w2b[idx] = f2bf(pw2[idx]);
}

// ---- spec -> specrb u32-packed bf16 pairs, layout [nb][k][i][o] ----
__global__ __launch_bounds__(256) void k_spectr(const float* __restrict__ spec,
                                                u32* __restrict__ specrb){
  const int bi = blockIdx.x;            // nb*128 + i
  const int t = threadIdx.x;
  __shared__ u32 sm[128*32];            // [o][k] swizzled, 16KB
  const float* src = spec + (size_t)bi*8192;   // [128o][32k][2]
  {
    const int o = t >> 1, kh = (t & 1)*16;
    const float* s = src + o*64 + kh*2;
    #pragma unroll
    for (int j = 0; j < 8; ++j){
      float4 v = *(const float4*)(s + j*4);
      u32 p0 = (u32)f2bf(v.x) | ((u32)f2bf(v.y)<<16);
      u32 p1 = (u32)f2bf(v.z) | ((u32)f2bf(v.w)<<16);
      int k0 = kh + 2*j;
      *(u32*)((char*)sm + o*128 + ((((k0>>2) ^ (o&7))&7)*16) + (k0&3)*4) = p0;
      int k1 = k0 + 1;
      *(u32*)((char*)sm + o*128 + ((((k1>>2) ^ (o&7))&7)*16) + (k1&3)*4) = p1;
    }
  }
  __syncthreads();
  {
    const int k = t >> 3, o0 = (t & 7)*16;
    u32 vals[16];
    #pragma unroll
    for (int j = 0; j < 16; ++j){
      int o = o0 + j;
      vals[j] = *(const u32*)((const char*)sm + o*128 + ((((k>>2) ^ (o&7))&7)*16) + (k&3)*4);
    }
    u32* dst = specrb + (size_t)(bi>>7)*524288 + ((size_t)k*128 + (bi&127))*128 + o0;
    #pragma unroll
    for (int j = 0; j < 4; ++j)
      *(uint4*)(dst + j*4) = make_uint4(vals[4*j], vals[4*j+1], vals[4*j+2], vals[4*j+3]);
  }
}

// ---- conditioning MLPs -> lifted (256x128) f32 ----
__global__ __launch_bounds__(128) void k_cond(const float* __restrict__ x,
    const float* __restrict__ ts,
    const float* __restrict__ w1, const float* __restrict__ b1,
    const float* __restrict__ w2, const float* __restrict__ b2,
    const float* __restrict__ lw, const float* __restrict__ lb,
    float* __restrict__ lifted){
  const int b = blockIdx.x, t = threadIdx.x;
  __shared__ float sp[64], cin[68], h[128], cond[128];
  const float* xr = x + b*68;
  if (t < 64) sp[t] = xr[t];
  if (t < 3)  cin[t] = xr[64+t];
  if (t >= 64 && t < 96){
    int j = t - 64;
    float tt = xr[67]*ts[0];
    float invf = exp2f(-(float)j*(13.287712379549449f/31.0f));
    float ang = tt*invf;
    cin[3+j]  = sinf(ang);
    cin[35+j] = cosf(ang);
  }
  __syncthreads();
  float acc = b1[t];
  for (int k = 0; k < 67; k++) acc += cin[k]*w1[t*67+k];
  h[t] = gelu_f(acc);
  __syncthreads();
  acc = b2[t];
  for (int k = 0; k < 128; k++) acc += h[k]*w2[t*128+k];
  cond[t] = acc;
  __syncthreads();
  acc = lb[t];
  const float* lwr = lw + t*192;
  for (int k = 0; k < 64; k++)  acc += sp[k]*lwr[k];
  for (int k = 0; k < 128; k++) acc += cond[k]*lwr[64+k];
  lifted[b*128 + t] = gelu_f(acc);
}

// ---- fr init (bf16): fr[b,l,c] = lifted[b,c] + POST[l,c] ----
__global__ __launch_bounds__(256) void k_frinit(const float* __restrict__ lifted,
    const float* __restrict__ POST, u16* __restrict__ fr){
  size_t idx = (size_t)blockIdx.x*256 + threadIdx.x;
  size_t e = idx*8;
  int b = (int)(e >> 17), l = (int)((e >> 7) & 1023), c = (int)(e & 127);
  const float* lf = lifted + b*128 + c;
  const float* pp = POST + l*128 + c;
  float4 a0 = *(const float4*)lf,  a1 = *(const float4*)(lf+4);
  float4 p0 = *(const float4*)pp,  p1 = *(const float4*)(pp+4);
  u32 o0 = (u32)f2bf(a0.x+p0.x) | ((u32)f2bf(a0.y+p0.y)<<16);
  u32 o1 = (u32)f2bf(a0.z+p0.z) | ((u32)f2bf(a0.w+p0.w)<<16);
  u32 o2 = (u32)f2bf(a1.x+p1.x) | ((u32)f2bf(a1.y+p1.y)<<16);
  u32 o3 = (u32)f2bf(a1.z+p1.z) | ((u32)f2bf(a1.w+p1.w)<<16);
  *(uint4*)(fr + e) = make_uint4(o0,o1,o2,o3);
}

// ---- DFT: ftp[h][b][q][c] bf16 = sum_l fr[b][l][c]*FtabT[q][l] (per l-half) ----
// grid (256 b, 2 h) x 512 thr (8 waves). LDS transpose of fr tiles.
__global__ __launch_bounds__(512) void k_dft(const u16* __restrict__ fr,
    const u16* __restrict__ FtabT, u16* __restrict__ ftp){
  const int t = threadIdx.x, w = t >> 6, lane = t & 63;
  const int nlo = lane & 15, kg = lane >> 4;
  const int b = blockIdx.x, h = blockIdx.y;
  const int q = (w & 3)*16 + nlo, chalf = w >> 2;
  const int lp = t >> 4, cg = t & 15;
  __shared__ u16 cT[128*64];   // [c][l-chunk] swizzled, 16KB
  f32x4 acc[4] = {};
  for (int ch = 0; ch < 8; ++ch){
    const int lbase = h*512 + ch*64;
    {
      const u16* r0 = fr + ((size_t)b*1024 + lbase + 2*lp)*128 + cg*8;
      uint4 A0 = *(const uint4*)r0;
      uint4 A1 = *(const uint4*)(r0 + 128);
      u32 a0[4] = {A0.x,A0.y,A0.z,A0.w};
      u32 a1[4] = {A1.x,A1.y,A1.z,A1.w};
      const int g = lp >> 2, bo = (lp & 3)*4;
      #pragma unroll
      for (int j = 0; j < 4; ++j){
        int c = cg*8 + 2*j;
        u32 lo = (a0[j] & 0xffffu) | (a1[j] << 16);
        u32 hi = (a0[j] >> 16)     | (a1[j] & 0xffff0000u);
        *(u32*)((char*)cT + c*128     + SWD(c,   g)*16 + bo) = lo;
        *(u32*)((char*)cT + (c+1)*128 + SWD(c+1, g)*16 + bo) = hi;
      }
    }
    __syncthreads();
    #pragma unroll
    for (int ks = 0; ks < 2; ++ks){
      bf16x8 bq = *(const bf16x8*)(FtabT + (size_t)q*1024 + lbase + ks*32 + kg*8);
      #pragma unroll
      for (int mf = 0; mf < 4; ++mf){
        int c = chalf*64 + mf*16 + nlo;
        bf16x8 a = *(const bf16x8*)((const char*)cT + c*128 + SWD(c, ks*4+kg)*16);
        acc[mf] = MFMA(a, bq, acc[mf]);
      }
    }
    __syncthreads();
  }
  u16* dst = ftp + (size_t)h*2097152 + ((size_t)b*64 + q)*128 + chalf*64;
  #pragma unroll
  for (int mf = 0; mf < 4; ++mf){
    u32 u01 = (u32)f2bf(acc[mf][0]) | ((u32)f2bf(acc[mf][1])<<16);
    u32 u23 = (u32)f2bf(acc[mf][2]) | ((u32)f2bf(acc[mf][3])<<16);
    *(uint2*)(dst + mf*16 + kg*4) = make_uint2(u01, u23);
  }
}

// ---- mode mix (fp32 VALU, bf16 in): oftb[b][o][64q] ----
__global__ __launch_bounds__(256) void k_modemm(const u16* __restrict__ ftp,
    const u32* __restrict__ specrb, u16* __restrict__ oftb){
  const int k = blockIdx.x;            // 0..31
  const int b0 = blockIdx.y*8;
  const int t = threadIdx.x;
  __shared__ float fA[128][17];
  {
    const int bl = t & 7, i0 = (t >> 3)*4;
    const u16* f0 = ftp + ((size_t)(b0+bl)*64 + 2*k)*128 + i0;
    uint2 re0 = *(const uint2*)f0;
    uint2 im0 = *(const uint2*)(f0 + 128);
    uint2 re1 = *(const uint2*)(f0 + 2097152);
    uint2 im1 = *(const uint2*)(f0 + 2097152 + 128);
    u32 r0[2] = {re0.x, re0.y}, i0v[2] = {im0.x, im0.y};
    u32 r1[2] = {re1.x, re1.y}, i1v[2] = {im1.x, im1.y};
    #pragma unroll
    for (int j = 0; j < 4; ++j){
      u32 ra = (j&1) ? (r0[j>>1]>>16)  : (r0[j>>1]&0xffffu);
      u32 rb = (j&1) ? (r1[j>>1]>>16)  : (r1[j>>1]&0xffffu);
      u32 ia = (j&1) ? (i0v[j>>1]>>16) : (i0v[j>>1]&0xffffu);
      u32 ib = (j&1) ? (i1v[j>>1]>>16) : (i1v[j>>1]&0xffffu);
      fA[i0+j][bl*2]   = bf2f(ra) + bf2f(rb);
      fA[i0+j][bl*2+1] = bf2f(ia) + bf2f(ib);
    }
  }
  __syncthreads();
  const int o = t & 127, bh = t >> 7;
  const u32* sp = specrb + (size_t)k*16384 + o;
  float accre[4] = {}, accim[4] = {};
  #pragma unroll 4
  for (int i = 0; i < 128; ++i){
    u32 wu = sp[(size_t)i*128];
    float wr = bf2f(wu & 0xffffu), wi = bf2f(wu >> 16);
    #pragma unroll
    for (int j = 0; j < 4; ++j){
      float2 a = *(const float2*)&fA[i][(bh*4+j)*2];
      accre[j] += a.x*wr - a.y*wi;
      accim[j] += a.x*wi + a.y*wr;
    }
  }
  #pragma unroll
  for (int j = 0; j < 4; ++j){
    u32 pk = (u32)f2bf(accre[j]) | ((u32)f2bf(accim[j])<<16);
    *(u32*)(oftb + ((size_t)(b0+bh*4+j)*128 + o)*64 + 2*k) = pk;
  }
}

// ---- combine: y = irfft(oft) + conv(fr) + cb; LN over o; gelu; fr in-place ----
// grid (16 ltiles, 256 b) x 256 thr. D[o][l]; all GEMM operands direct.
__global__ __launch_bounds__(256) void k_combine(u16* __restrict__ fr,
    const u16* __restrict__ oftb, const u16* __restrict__ cwb,
    const float* __restrict__ cb, const float* __restrict__ g,
    const float* __restrict__ bt, const u16* __restrict__ GT){
  const int l0 = blockIdx.x*64, b = blockIdx.y;
  const int t = threadIdx.x, w = t >> 6, lane = t & 63;
  const int nlo = lane & 15, kg = lane >> 4;
  __shared__ char smem[18944];
  u16* ys     = (u16*)smem;              // [64l][128c] swizzled, 16KB
  float* red  = (float*)(smem + 16384);  // [4][64][2]
  float* stats= (float*)(smem + 18432);  // [64][2]

  f32x4 acc[2][4] = {};   // [mfo][nfl]
  // K-part 1: irfft basis (q)
  #pragma unroll
  for (int ki = 0; ki < 2; ++ki){
    bf16x8 a0 = *(const bf16x8*)(oftb + ((size_t)b*128 + w*32 +      nlo)*64 + ki*32 + kg*8);
    bf16x8 a1 = *(const bf16x8*)(oftb + ((size_t)b*128 + w*32 + 16 + nlo)*64 + ki*32 + kg*8);
    #pragma unroll
    for (int nfl = 0; nfl < 4; ++nfl){
      bf16x8 bgt = *(const bf16x8*)(GT + (size_t)(l0 + nfl*16 + nlo)*64 + ki*32 + kg*8);
      acc[0][nfl] = MFMA(a0, bgt, acc[0][nfl]);
      acc[1][nfl] = MFMA(a1, bgt, acc[1][nfl]);
    }
  }
  // K-part 2: conv (c)
  #pragma unroll
  for (int ki = 0; ki < 4; ++ki){
    bf16x8 a0 = *(const bf16x8*)(cwb + (w*32 +      nlo)*128 + ki*32 + kg*8);
    bf16x8 a1 = *(const bf16x8*)(cwb + (w*32 + 16 + nlo)*128 + ki*32 + kg*8);
    #pragma unroll
    for (int nfl = 0; nfl < 4; ++nfl){
      bf16x8 bf = *(const bf16x8*)(fr + ((size_t)b*1024 + l0 + nfl*16 + nlo)*128 + ki*32 + kg*8);
      acc[0][nfl] = MFMA(a0, bf, acc[0][nfl]);
      acc[1][nfl] = MFMA(a1, bf, acc[1][nfl]);
    }
  }

  // bias + LN sums
  float4 cb4[2] = { *(const float4*)&cb[w*32 + kg*4], *(const float4*)&cb[w*32 + 16 + kg*4] };
  float s[4], s2[4];
  #pragma unroll
  for (int nfl = 0; nfl < 4; ++nfl){
    float ss = 0.f, ss2 = 0.f;
    #pragma unroll
    for (int mfo = 0; mfo < 2; ++mfo)
      #pragma unroll
      for (int r = 0; r < 4; ++r){
        float v = acc[mfo][nfl][r] + cb4[mfo][r];
        acc[mfo][nfl][r] = v;
        ss += v; ss2 += v*v;
      }
    ss  += __shfl_xor(ss, 16);  ss  += __shfl_xor(ss, 32);
    ss2 += __shfl_xor(ss2, 16); ss2 += __shfl_xor(ss2, 32);
    s[nfl] = ss; s2[nfl] = ss2;
  }
  if (lane < 16){
    #pragma unroll
    for (int nfl = 0; nfl < 4; ++nfl){
      red[(w*64 + nfl*16 + nlo)*2 + 0] = s[nfl];
      red[(w*64 + nfl*16 + nlo)*2 + 1] = s2[nfl];
    }
  }
  __syncthreads();
  if (t < 64){
    float ss  = red[t*2]   + red[(64+t)*2]   + red[(128+t)*2]   + red[(192+t)*2];
    float ss2 = red[t*2+1] + red[(64+t)*2+1] + red[(128+t)*2+1] + red[(192+t)*2+1];
    float mu = ss*(1.0f/128.0f);
    float var = ss2*(1.0f/128.0f) - mu*mu;
    stats[t*2+0] = mu;
    stats[t*2+1] = rsqrtf(var + 1e-5f);
  }
  __syncthreads();

  float4 g4[2]  = { *(const float4*)&g[w*32 + kg*4],  *(const float4*)&g[w*32 + 16 + kg*4] };
  float4 bt4[2] = { *(const float4*)&bt[w*32 + kg*4], *(const float4*)&bt[w*32 + 16 + kg*4] };
  #pragma unroll
  for (int nfl = 0; nfl < 4; ++nfl){
    const int l = nfl*16 + nlo;
    float2 st = *(const float2*)&stats[l*2];
    #pragma unroll
    for (int mfo = 0; mfo < 2; ++mfo){
      float vs[4];
      #pragma unroll
      for (int r = 0; r < 4; ++r)
        vs[r] = gelu_f((acc[mfo][nfl][r] - st.x)*st.y*g4[mfo][r] + bt4[mfo][r]);
      u32 u01 = (u32)f2bf(vs[0]) | ((u32)f2bf(vs[1])<<16);
      u32 u23 = (u32)f2bf(vs[2]) | ((u32)f2bf(vs[3])<<16);
      int c0 = w*32 + mfo*16 + kg*4;
      int byteoff = l*256 + (((c0>>3) ^ SW3(l))*16) + (c0&4)*2;
      *(uint2*)((char*)ys + byteoff) = make_uint2(u01, u23);
    }
  }
  __syncthreads();
  // coalesced writeback
  {
    const int lr = t >> 2, q4 = t & 3;
    u16* dst = fr + ((size_t)b*1024 + l0 + lr)*128 + q4*32;
    #pragma unroll
    for (int j = 0; j < 4; ++j){
      uint4 v = *(const uint4*)((const char*)ys + lr*256 + (((q4*4+j) ^ SW3(lr))*16));
      *(uint4*)(dst + j*8) = v;
    }
  }
}

// ---- out init: out = sp + proj_b2 ----
__global__ void k_initout(const float* __restrict__ x,
    const float* __restrict__ b2, float* __restrict__ out){
  int idx = blockIdx.x*256 + threadIdx.x;
  if (idx < 256*64){
    int b = idx >> 6, o = idx & 63;
    out[idx] = x[b*68 + o] + b2[o];
  }
}

// ---- projection (MFMA, direct operands) + mean over L ----
__global__ __launch_bounds__(256) void k_proj(const u16* __restrict__ fr,
    const u16* __restrict__ w1b, const float* __restrict__ pb1,
    const u16* __restrict__ w2b, float* __restrict__ out){
  const int l0 = blockIdx.x*64, b = blockIdx.y;
  const int t = threadIdx.x, w = t >> 6, lane = t & 63;
  const int nlo = lane & 15, kg = lane >> 4;
  __shared__ u16 h2s[64*64];   // [l][h] swizzled, 8KB
  const int lB = l0 + w*16 + nlo;

  f32x4 acc1[4] = {};
  #pragma unroll
  for (int ki = 0; ki < 4; ++ki){
    bf16x8 bf = *(const bf16x8*)(fr + ((size_t)b*1024 + lB)*128 + ki*32 + kg*8);
    #pragma unroll
    for (int mfh = 0; mfh < 4; ++mfh){
      bf16x8 a = *(const bf16x8*)(w1b + (mfh*16 + nlo)*128 + ki*32 + kg*8);
      acc1[mfh] = MFMA(a, bf, acc1[mfh]);
    }
  }
  const int lw = w*16 + nlo;
  #pragma unroll
  for (int mfh = 0; mfh < 4; ++mfh){
    float4 b1v = *(const float4*)&pb1[mfh*16 + kg*4];
    float vs[4];
    #pragma unroll
    for (int r = 0; r < 4; ++r) vs[r] = gelu_f(acc1[mfh][r] + b1v[r]);
    u32 u01 = (u32)f2bf(vs[0]) | ((u32)f2bf(vs[1])<<16);
    u32 u23 = (u32)f2bf(vs[2]) | ((u32)f2bf(vs[3])<<16);
    int h0 = mfh*16 + kg*4;
    int byteoff = lw*128 + ((((h0>>3) ^ SWP(lw))&7)*16) + (h0&4)*2;
    *(uint2*)((char*)h2s + byteoff) = make_uint2(u01, u23);
  }
  __syncthreads();

  f32x4 acc2[4] = {};
  #pragma unroll
  for (int ki = 0; ki < 2; ++ki){
    bf16x8 bh = *(const bf16x8*)((const char*)h2s + lw*128 + ((((ki*4+kg) ^ SWP(lw))&7)*16));
    #pragma unroll
    for (int mfo = 0; mfo < 4; ++mfo){
      bf16x8 a = *(const bf16x8*)(w2b + (mfo*16 + nlo)*64 + ki*32 + kg*8);
      acc2[mfo] = MFMA(a, bh, acc2[mfo]);
    }
  }
  #pragma unroll
  for (int mfo = 0; mfo < 4; ++mfo)
    #pragma unroll
    for (int r = 0; r < 4; ++r){
      float v = acc2[mfo][r];
      v += __shfl_xor(v, 1); v += __shfl_xor(v, 2);
      v += __shfl_xor(v, 4); v += __shfl_xor(v, 8);
      if (nlo == 0)
        atomicAdd(out + (size_t)b*64 + mfo*16 + kg*4 + r, v*(1.0f/1024.0f));
    }
}

extern "C" void kernel_launch(void* const* d_in, const int* in_sizes, int n_in,
                              void* d_out, int out_size, void* d_ws, size_t ws_size,
                              hipStream_t stream){
  const float* x    = (const float*)d_in[0];
  const float* ts   = (const float*)d_in[1];
  const float* cw1  = (const float*)d_in[2];
  const float* cb1  = (const float*)d_in[3];
  const float* cw2  = (const float*)d_in[4];
  const float* cb2  = (const float*)d_in[5];
  const float* lw   = (const float*)d_in[6];
  const float* lb   = (const float*)d_in[7];
  const float* spec = (const float*)d_in[8];
  const float* conw = (const float*)d_in[9];
  const float* conb = (const float*)d_in[10];
  const float* lng  = (const float*)d_in[11];
  const float* lnb  = (const float*)d_in[12];
  const float* pw1  = (const float*)d_in[13];
  const float* pb1  = (const float*)d_in[14];
  const float* pw2  = (const float*)d_in[15];
  const float* pb2  = (const float*)d_in[16];

  char* W = (char*)d_ws;
  u16*   fr     = (u16*)  (W);                    // 67,108,864 B
  u16*   ftp    = (u16*)  (W + 67108864);         //  8,388,608 B (2 halves bf16)
  u16*   oftb   = (u16*)  (W + 75497472);         //  4,194,304 B
  float* lifted = (float*)(W + 79691776);         //    131,072 B
  float* POST   = (float*)(W + 79822848);         //    524,288 B
  u16*   FtabT  = (u16*)  (W + 80347136);         //    131,072 B
  u16*   GT     = (u16*)  (W + 80478208);         //    131,072 B
  u16*   cwb    = (u16*)  (W + 80609280);         //    131,072 B
  u16*   w1b    = (u16*)  (W + 80740352);         //     16,384 B
  u16*   w2b    = (u16*)  (W + 80756736);         //      8,192 B
  u32*   specrb = (u32*)  (W + 80764928);         //  8,388,608 B (~85 MB tot)

  hipLaunchKernelGGL(k_tables, dim3(512), dim3(256), 0, stream,
                     POST, FtabT, GT, conw, cwb, pw1, w1b, pw2, w2b);
  hipLaunchKernelGGL(k_spectr, dim3(512), dim3(256), 0, stream, spec, specrb);
  hipLaunchKernelGGL(k_cond, dim3(256), dim3(128), 0, stream,
                     x, ts, cw1, cb1, cw2, cb2, lw, lb, lifted);
  hipLaunchKernelGGL(k_frinit, dim3(16384), dim3(256), 0, stream, lifted, POST, fr);
  for (int nb = 0; nb < 4; nb++){
    hipLaunchKernelGGL(k_dft, dim3(256,2), dim3(512), 0, stream, fr, FtabT, ftp);
    hipLaunchKernelGGL(k_modemm, dim3(32,32), dim3(256), 0, stream,
                       ftp, specrb + (size_t)nb*524288, oftb);
    hipLaunchKernelGGL(k_combine, dim3(16,256), dim3(256), 0, stream,
                       fr, oftb, cwb + nb*16384, conb + nb*128,
                       lng + nb*128, lnb + nb*128, GT);
  }
  hipLaunchKernelGGL(k_initout, dim3(64), dim3(256), 0, stream, x, pb2, (float*)d_out);
  hipLaunchKernelGGL(k_proj, dim3(16,256), dim3(256), 0, stream,
                     fr, w1b, pb1, w2b, (float*)d_out);
}